// Round 12
// baseline (69.173 us; speedup 1.0000x reference)
//
#include <hip/hip_runtime.h>
#include <hip/hip_fp16.h>

#define IN_F   4096
#define OUT_F  11008
#define BATCH  16
#define GROUPS 32                    // 4096 / 128
#define PPR    2048                  // packed int32 per output row (IN_F/2)

typedef __attribute__((ext_vector_type(8))) _Float16 half8;
typedef __attribute__((ext_vector_type(2))) _Float16 h2;
typedef __attribute__((ext_vector_type(4))) float    float4_t;
typedef __attribute__((ext_vector_type(4))) int      int4_t;
typedef __attribute__((ext_vector_type(4))) unsigned uint4_t;

__device__ inline h2 cvt2(float a, float b) {
    return __builtin_bit_cast(h2, __builtin_amdgcn_cvt_pkrtz(a, b));
}

// async global->LDS, 16B per lane, dest = uniform base + lane*16
#define GLOAD_LDS(srcp, ldsp) \
    __builtin_amdgcn_global_load_lds( \
        (const __attribute__((address_space(1))) void*)(srcp), \
        (__attribute__((address_space(3))) void*)(ldsp), 16, 0, 0)

// ---- pre-pass: x (16x4096 f32) -> f16 table in FRAGMENT order ----
__global__ __launch_bounds__(256) void xcvt_perm(const float* __restrict__ x,
                                                 _Float16* __restrict__ xp) {
    const int T = blockIdx.x * 256 + threadIdx.x;   // 8192 threads
    const int step = T >> 6, lane = T & 63;
    const int b = lane & 15, k = step * 32 + (lane >> 4) * 8;
    const float4_t a0 = *(const float4_t*)(x + b * IN_F + k);
    const float4_t a1 = *(const float4_t*)(x + b * IN_F + k + 4);
    half8 h;
    h2 p0 = cvt2(a0.x, a0.y), p1 = cvt2(a0.z, a0.w);
    h2 p2 = cvt2(a1.x, a1.y), p3 = cvt2(a1.z, a1.w);
    h[0]=p0[0]; h[1]=p0[1]; h[2]=p1[0]; h[3]=p1[1];
    h[4]=p2[0]; h[5]=p2[1]; h[6]=p3[0]; h[7]=p3[1];
    *(half8*)(xp + step * 512 + lane * 8) = h;
}

// ---- DIAGNOSTIC build of the R10 single-pass gemm: body repeats 3x so the
// dispatch (~3x gemm time) surfaces above the harness's 51us fillBuffer rows
// in the top-5 rocprof table. Same values stored every rep -> output
// unchanged. vmcnt(0) at each rep top drains epilogue stores so the counted
// vmcnt(8) arithmetic stays exact. Epilogue __syncthreads orders LDS reuse.
__global__ __launch_bounds__(256, 4) void gptq_gemm_full(
    const _Float16* __restrict__ xp, const int* __restrict__ qw,
    const float* __restrict__ scales, const float* __restrict__ zeros,
    const float* __restrict__ bias, float* __restrict__ out)
{
    __shared__ int   lq[2][16 * 256];    // 2 x 16KB swizzled q tiles
    __shared__ float red[4][16][17];

    const int tid  = threadIdx.x;
    const int lane = tid & 63, wave = tid >> 6;
    const int otile = blockIdx.x;
    const int ln = lane & 15, lk = lane >> 4;
    const int o  = otile * 16 + ln;
    const int x3 = ln & 7;

    // 8 (s,z) pairs for this wave: group g = c*4 + wave, c = 0..7
    h2 s2g[8], c2g[8];
    #pragma unroll
    for (int c = 0; c < 8; ++c) {
        const float s = scales[o * GROUPS + c * 4 + wave];
        const float z = zeros [o * GROUPS + c * 4 + wave];
        s2g[c] = cvt2(s, s);
        c2g[c] = cvt2(-z * s, -z * s);        // w = q*s + (-z*s)
    }
    const h2 k1024 = { (_Float16)1024.0f, (_Float16)1024.0f };

    half8 xv[2][4];

#define STAGE(C, BUF) { \
    _Pragma("unroll") \
    for (int i = 0; i < 4; ++i) { \
        const int row = wave * 4 + i; \
        const int* s0 = qw + (otile * 16 + row) * PPR + (C) * 256 \
                      + ((lane ^ (row & 7)) * 4); \
        GLOAD_LDS(s0, &lq[BUF][row * 256]); \
    } \
    __builtin_amdgcn_sched_barrier(0); }

#define XLOAD(C, BUF) { \
    const char* xc = (const char*)xp + ((C) * 16 + wave * 4) * 1024 + lane * 16; \
    asm volatile("global_load_dwordx4 %0, %1, off"             : "=v"(xv[BUF][0]) : "v"(xc)); \
    asm volatile("global_load_dwordx4 %0, %1, off offset:1024" : "=v"(xv[BUF][1]) : "v"(xc)); \
    asm volatile("global_load_dwordx4 %0, %1, off offset:2048" : "=v"(xv[BUF][2]) : "v"(xc)); \
    asm volatile("global_load_dwordx4 %0, %1, off offset:3072" : "=v"(xv[BUF][3]) : "v"(xc)); \
    __builtin_amdgcn_sched_barrier(0); }

#define WAITV8 { asm volatile("s_waitcnt vmcnt(8)" ::: "memory"); \
                 __builtin_amdgcn_sched_barrier(0); }
#define WAITV0 { asm volatile("s_waitcnt vmcnt(0)" ::: "memory"); \
                 __builtin_amdgcn_sched_barrier(0); }
#define BARR   { __builtin_amdgcn_s_barrier(); \
                 __builtin_amdgcn_sched_barrier(0); }

#define COMPUTE(C, BUF) { \
    _Pragma("unroll") \
    for (int t = 0; t < 4; ++t) { \
        const int4_t v = *(const int4_t*)((const char*)lq + (BUF) * 16384 \
            + ln * 1024 + (((wave * 16 + t * 4 + lk) ^ x3) << 4)); \
        uint4_t bw; \
        _Pragma("unroll") \
        for (int i = 0; i < 4; ++i) { \
            const unsigned pv = (unsigned)v[i]; \
            const unsigned u = (pv & 0xFu) | ((pv << 12) & 0xF0000u) \
                             | 0x64006400u;            /* {1024+qlo,1024+qhi} */ \
            h2 q = __builtin_bit_cast(h2, u) - k1024;  /* exact {qlo,qhi} */ \
            h2 w = q * s2g[C] + c2g[C];                /* v_pk_fma_f16 */ \
            bw[i] = __builtin_bit_cast(unsigned, w); \
        } \
        acc = __builtin_amdgcn_mfma_f32_16x16x32_f16( \
            xv[BUF][t], __builtin_bit_cast(half8, bw), acc, 0, 0, 0); \
    } }

    #pragma unroll 1
    for (int rep = 0; rep < 3; ++rep) {
        asm volatile("" ::: "memory");                 // no CSE across reps
        asm volatile("s_waitcnt vmcnt(0)" ::: "memory"); // drain stores/scalars
        __builtin_amdgcn_sched_barrier(0);             // -> vmcnt counts exact

        float4_t acc = {0.f, 0.f, 0.f, 0.f};

        STAGE(0, 0) XLOAD(0, 0)      //  8 in flight
        STAGE(1, 1) XLOAD(1, 1)      // 16 in flight

        WAITV8 BARR COMPUTE(0, 0) BARR STAGE(2, 0) XLOAD(2, 0)
        WAITV8 BARR COMPUTE(1, 1) BARR STAGE(3, 1) XLOAD(3, 1)
        WAITV8 BARR COMPUTE(2, 0) BARR STAGE(4, 0) XLOAD(4, 0)
        WAITV8 BARR COMPUTE(3, 1) BARR STAGE(5, 1) XLOAD(5, 1)
        WAITV8 BARR COMPUTE(4, 0) BARR STAGE(6, 0) XLOAD(6, 0)
        WAITV8 BARR COMPUTE(5, 1) BARR STAGE(7, 1) XLOAD(7, 1)
        WAITV8 BARR COMPUTE(6, 0) BARR
        WAITV0 BARR COMPUTE(7, 1)

        // cross-wave k-reduce; lane holds D[(l>>4)*4+r][l&15]
        #pragma unroll
        for (int r = 0; r < 4; ++r) red[wave][lk * 4 + r][ln] = acc[r];
        __syncthreads();                               // also orders LDS reuse

        const int row = tid >> 4, col = tid & 15;
        const float sum = red[0][row][col] + red[1][row][col]
                        + red[2][row][col] + red[3][row][col];
        const int oo = otile * 16 + col;
        out[row * OUT_F + oo] = sum + bias[oo];        // same values each rep
        __syncthreads();                               // red[] reuse ordering
    }

#undef STAGE
#undef XLOAD
#undef WAITV8
#undef WAITV0
#undef BARR
#undef COMPUTE
}

// ---- fallback (no workspace): 4-wave single-pass kernel ----
__global__ __launch_bounds__(256) void gptq_gemm_fb(
    const float* __restrict__ x, const int* __restrict__ qw,
    const float* __restrict__ scales, const float* __restrict__ zeros,
    const float* __restrict__ bias, float* __restrict__ out)
{
    const int tid  = threadIdx.x;
    const int lane = tid & 63;
    const int wave = tid >> 6;
    const int otile = blockIdx.x;
    const int ln = lane & 15, lk = lane >> 4;
    const int o = otile * 16 + ln;
    const int kc0 = wave * 1024;

    const int* qbase = qw + o * PPR + (kc0 >> 1) + lk * 4;
    const float* srow = scales + o * GROUPS;
    const float* zrow = zeros  + o * GROUPS;

    float4_t acc = {0.f, 0.f, 0.f, 0.f};
    const h2 k1024 = { (_Float16)1024.0f, (_Float16)1024.0f };

    #pragma unroll
    for (int ch = 0; ch < 4; ++ch) {
        const int cc = kc0 + ch * 256;
        h2 s2[2], c2[2];
        #pragma unroll
        for (int gi = 0; gi < 2; ++gi) {
            const float s  = srow[(cc >> 7) + gi];
            const float c0 = -zrow[(cc >> 7) + gi] * s;
            s2[gi] = cvt2(s, s); c2[gi] = cvt2(c0, c0);
        }
        #pragma unroll
        for (int t = 0; t < 8; ++t) {
            const int4_t v = *(const int4_t*)(qbase + ch * 128 + t * 16);
            const float* xq = x + ln * IN_F + cc + t * 32 + lk * 8;
            const float4_t a0 = *(const float4_t*)(xq);
            const float4_t a1 = *(const float4_t*)(xq + 4);
            half8 af;
            h2 p0 = cvt2(a0.x, a0.y), p1 = cvt2(a0.z, a0.w);
            h2 p2 = cvt2(a1.x, a1.y), p3 = cvt2(a1.z, a1.w);
            af[0]=p0[0]; af[1]=p0[1]; af[2]=p1[0]; af[3]=p1[1];
            af[4]=p2[0]; af[5]=p2[1]; af[6]=p3[0]; af[7]=p3[1];
            const int gi = t >> 2;
            uint4_t bw;
            #pragma unroll
            for (int i = 0; i < 4; ++i) {
                const unsigned pv = (unsigned)v[i];
                const unsigned u = (pv & 0xFu) | ((pv << 12) & 0xF0000u)
                                 | 0x64006400u;
                h2 q = __builtin_bit_cast(h2, u) - k1024;
                h2 w = q * s2[gi] + c2[gi];
                bw[i] = __builtin_bit_cast(unsigned, w);
            }
            acc = __builtin_amdgcn_mfma_f32_16x16x32_f16(
                af, __builtin_bit_cast(half8, bw), acc, 0, 0, 0);
        }
    }

    __shared__ float red[4][16][17];
    #pragma unroll
    for (int r = 0; r < 4; ++r) red[wave][lk * 4 + r][ln] = acc[r];
    __syncthreads();
    const int row = tid >> 4, col = tid & 15;
    const float sum = red[0][row][col] + red[1][row][col]
                    + red[2][row][col] + red[3][row][col];
    const int oo = otile * 16 + col;
    out[row * OUT_F + oo] = sum + bias[oo];
}

extern "C" void kernel_launch(void* const* d_in, const int* in_sizes, int n_in,
                              void* d_out, int out_size, void* d_ws, size_t ws_size,
                              hipStream_t stream) {
    const float* x      = (const float*)d_in[0];
    const int*   qwgt   = (const int*)d_in[1];
    const float* scales = (const float*)d_in[2];
    const float* zeros  = (const float*)d_in[3];
    const float* bias   = (const float*)d_in[4];
    float* out = (float*)d_out;

    const int nOTiles = OUT_F / 16;                    // 688

    if (d_ws && ws_size >= (size_t)(1 << 20)) {
        _Float16* xp = (_Float16*)d_ws;                // 128 KB f16 x table
        hipLaunchKernelGGL(xcvt_perm, dim3(32), dim3(256), 0, stream, x, xp);
        hipLaunchKernelGGL(gptq_gemm_full, dim3(nOTiles), dim3(256), 0, stream,
                           xp, qwgt, scales, zeros, bias, out);
    } else {
        hipLaunchKernelGGL(gptq_gemm_fb, dim3(nOTiles), dim3(256), 0, stream,
                           x, qwgt, scales, zeros, bias, out);
    }
}

// Round 13
// 33.493 us; speedup vs baseline: 2.0653x; 2.0653x over previous
//
#include <hip/hip_runtime.h>
#include <hip/hip_fp16.h>

#define IN_F   4096
#define OUT_F  11008
#define BATCH  16
#define GROUPS 32                    // 4096 / 128
#define PPR    2048                  // packed int32 per output row (IN_F/2)

typedef __attribute__((ext_vector_type(8))) _Float16 half8;
typedef __attribute__((ext_vector_type(2))) _Float16 h2;
typedef __attribute__((ext_vector_type(4))) float    float4_t;
typedef __attribute__((ext_vector_type(4))) int      int4_t;
typedef __attribute__((ext_vector_type(4))) unsigned uint4_t;

__device__ inline h2 cvt2(float a, float b) {
    return __builtin_bit_cast(h2, __builtin_amdgcn_cvt_pkrtz(a, b));
}

// async global->LDS, 16B per lane, dest = uniform base + lane*16
#define GLOAD_LDS(srcp, ldsp) \
    __builtin_amdgcn_global_load_lds( \
        (const __attribute__((address_space(1))) void*)(srcp), \
        (__attribute__((address_space(3))) void*)(ldsp), 16, 0, 0)

// ---- pre-pass: x (16x4096 f32) -> f16 table in FRAGMENT order ----
// step s (32 k-cols), lane l: xp[s*512 + l*8 .. +8) = f16 x[b=l&15]
// [k = s*32 + (l>>4)*8 .. +8). Gemm A-fragment load = ONE contiguous 1KB req.
__global__ __launch_bounds__(256) void xcvt_perm(const float* __restrict__ x,
                                                 _Float16* __restrict__ xp) {
    const int T = blockIdx.x * 256 + threadIdx.x;   // 8192 threads
    const int step = T >> 6, lane = T & 63;
    const int b = lane & 15, k = step * 32 + (lane >> 4) * 8;
    const float4_t a0 = *(const float4_t*)(x + b * IN_F + k);
    const float4_t a1 = *(const float4_t*)(x + b * IN_F + k + 4);
    half8 h;
    h2 p0 = cvt2(a0.x, a0.y), p1 = cvt2(a0.z, a0.w);
    h2 p2 = cvt2(a1.x, a1.y), p3 = cvt2(a1.z, a1.w);
    h[0]=p0[0]; h[1]=p0[1]; h[2]=p1[0]; h[3]=p1[1];
    h[4]=p2[0]; h[5]=p2[1]; h[6]=p3[0]; h[7]=p3[1];
    *(half8*)(xp + step * 512 + lane * 8) = h;
}

// ---- single-pass gemm, occupancy-first (R12 diagnostic: TLP was the limit).
// Block = otile, 8 waves (512 thr), __launch_bounds__(512,8) -> 4 blocks/CU
// = 32 waves/CU (100%); 688 blocks all co-resident (capacity 1024), no tail.
// K = 8 chunks x 512 cols, LDS dbuf 2x16KB (=32KB -> exactly 4 blocks/CU).
// Wave w computes cols [c*512+w*64,+64) (one group, 2 MFMA) of every chunk,
// stages rows 2w,2w+1 (1KB each). Counted vmcnt(4) keeps next chunk in
// flight across all barriers. Swizzle: row r staged from src slot lane^r,
// read at slot s^ln -> 2 lanes/bank-group (free, m136).
__global__ __launch_bounds__(512, 8) void gptq_gemm_full(
    const _Float16* __restrict__ xp, const int* __restrict__ qw,
    const float* __restrict__ scales, const float* __restrict__ zeros,
    const float* __restrict__ bias, float* __restrict__ out)
{
    __shared__ int lq[2][16 * 256];      // 2 x 16KB; buf0 reused as red[]

    const int tid  = threadIdx.x;
    const int lane = tid & 63, wave = tid >> 6;   // wave 0..7
    const int otile = blockIdx.x;
    const int ln = lane & 15, lk = lane >> 4;
    const int o  = otile * 16 + ln;

    // per-chunk group constants: wave w, chunk c -> group c*4 + (w>>1)
    h2 s2g[8], c2g[8];
    #pragma unroll
    for (int c = 0; c < 8; ++c) {
        const int g = c * 4 + (wave >> 1);
        const float s = scales[o * GROUPS + g];
        const float z = zeros [o * GROUPS + g];
        s2g[c] = cvt2(s, s);
        c2g[c] = cvt2(-z * s, -z * s);            // w = q*s + (-z*s)
    }
    const h2 k1024 = { (_Float16)1024.0f, (_Float16)1024.0f };

    asm volatile("s_waitcnt vmcnt(0)" ::: "memory");   // consts retired
    __builtin_amdgcn_sched_barrier(0);                 // -> vmcnt exact

    half8 xvA0, xvA1, xvB0, xvB1;
    float4_t acc = {0.f, 0.f, 0.f, 0.f};

// stage chunk C: this wave stages rows 2w, 2w+1 (1KB each). Lane l writes
// phys slot l of its row; source slot = l ^ r (inv-swizzle, T21).
#define STAGE(C, BUF) { \
    _Pragma("unroll") \
    for (int i = 0; i < 2; ++i) { \
        const int r = wave * 2 + i; \
        const int* src = qw + (otile * 16 + r) * PPR + (C) * 256 \
                       + ((lane ^ r) * 4); \
        GLOAD_LDS(src, &lq[BUF][r * 256]); \
    } \
    __builtin_amdgcn_sched_barrier(0); }

// 2 x-fragment loads for chunk C (global steps C*16 + wave*2 + {0,1})
#define XLOAD(C, N0, N1) { \
    const char* xc = (const char*)xp + ((C) * 16 + wave * 2) * 1024 + lane * 16; \
    asm volatile("global_load_dwordx4 %0, %1, off"             : "=v"(N0) : "v"(xc)); \
    asm volatile("global_load_dwordx4 %0, %1, off offset:1024" : "=v"(N1) : "v"(xc)); \
    __builtin_amdgcn_sched_barrier(0); }

#define WAITV4 { asm volatile("s_waitcnt vmcnt(4)" ::: "memory"); \
                 __builtin_amdgcn_sched_barrier(0); }
#define WAITV0 { asm volatile("s_waitcnt vmcnt(0)" ::: "memory"); \
                 __builtin_amdgcn_sched_barrier(0); }
#define BARR   { __builtin_amdgcn_s_barrier(); \
                 __builtin_amdgcn_sched_barrier(0); }

// one 32-col step: slot s = wave*8 + T*4 + lk, read phys s^ln of row ln
#define STEP(C, BUF, T, XF) { \
    const int4_t v = *(const int4_t*)((const char*)lq + (BUF) * 16384 \
        + ln * 1024 + (((wave * 8 + (T) * 4 + lk) ^ ln) << 4)); \
    uint4_t bw; \
    _Pragma("unroll") \
    for (int i = 0; i < 4; ++i) { \
        const unsigned pv = (unsigned)v[i]; \
        const unsigned u = (pv & 0xFu) | ((pv << 12) & 0xF0000u) \
                         | 0x64006400u;            /* {1024+qlo,1024+qhi} */ \
        h2 q = __builtin_bit_cast(h2, u) - k1024;  /* exact {qlo,qhi} */ \
        h2 w = q * s2g[C] + c2g[C];                /* v_pk_fma_f16 */ \
        bw[i] = __builtin_bit_cast(unsigned, w); \
    } \
    acc = __builtin_amdgcn_mfma_f32_16x16x32_f16( \
        (XF), __builtin_bit_cast(half8, bw), acc, 0, 0, 0); }

#define COMPA(C) { STEP(C, 0, 0, xvA0) STEP(C, 0, 1, xvA1) }
#define COMPB(C) { STEP(C, 1, 0, xvB0) STEP(C, 1, 1, xvB1) }

    STAGE(0, 0) XLOAD(0, xvA0, xvA1)     // 4 in flight
    STAGE(1, 1) XLOAD(1, xvB0, xvB1)     // 8 in flight

    WAITV4 BARR COMPA(0) BARR STAGE(2, 0) XLOAD(2, xvA0, xvA1)
    WAITV4 BARR COMPB(1) BARR STAGE(3, 1) XLOAD(3, xvB0, xvB1)
    WAITV4 BARR COMPA(2) BARR STAGE(4, 0) XLOAD(4, xvA0, xvA1)
    WAITV4 BARR COMPB(3) BARR STAGE(5, 1) XLOAD(5, xvB0, xvB1)
    WAITV4 BARR COMPA(4) BARR STAGE(6, 0) XLOAD(6, xvA0, xvA1)
    WAITV4 BARR COMPB(5) BARR STAGE(7, 1) XLOAD(7, xvB0, xvB1)
    WAITV4 BARR COMPA(6) BARR
    WAITV0 BARR COMPB(7)

#undef STAGE
#undef XLOAD
#undef WAITV4
#undef WAITV0
#undef BARR
#undef STEP
#undef COMPA
#undef COMPB

    // 8-way cross-wave reduce in buf0 (dead: last compute read buf1).
    // C/D layout (m89-verified): lane holds D[(l>>4)*4 + r][l&15].
    float* red = (float*)lq;             // red[8][16][17]
    #pragma unroll
    for (int r = 0; r < 4; ++r)
        red[wave * 272 + (lk * 4 + r) * 17 + ln] = acc[r];
    __syncthreads();

    if (tid < 256) {
        const int row = tid >> 4, col = tid & 15;
        float s = bias[otile * 16 + col];
        #pragma unroll
        for (int w = 0; w < 8; ++w) s += red[w * 272 + row * 17 + col];
        out[row * OUT_F + otile * 16 + col] = s;
    }
}

// ---- fallback (no workspace): 4-wave single-pass kernel ----
__global__ __launch_bounds__(256) void gptq_gemm_fb(
    const float* __restrict__ x, const int* __restrict__ qw,
    const float* __restrict__ scales, const float* __restrict__ zeros,
    const float* __restrict__ bias, float* __restrict__ out)
{
    const int tid  = threadIdx.x;
    const int lane = tid & 63;
    const int wave = tid >> 6;
    const int otile = blockIdx.x;
    const int ln = lane & 15, lk = lane >> 4;
    const int o = otile * 16 + ln;
    const int kc0 = wave * 1024;

    const int* qbase = qw + o * PPR + (kc0 >> 1) + lk * 4;
    const float* srow = scales + o * GROUPS;
    const float* zrow = zeros  + o * GROUPS;

    float4_t acc = {0.f, 0.f, 0.f, 0.f};
    const h2 k1024 = { (_Float16)1024.0f, (_Float16)1024.0f };

    #pragma unroll
    for (int ch = 0; ch < 4; ++ch) {
        const int cc = kc0 + ch * 256;
        h2 s2[2], c2[2];
        #pragma unroll
        for (int gi = 0; gi < 2; ++gi) {
            const float s  = srow[(cc >> 7) + gi];
            const float c0 = -zrow[(cc >> 7) + gi] * s;
            s2[gi] = cvt2(s, s); c2[gi] = cvt2(c0, c0);
        }
        #pragma unroll
        for (int t = 0; t < 8; ++t) {
            const int4_t v = *(const int4_t*)(qbase + ch * 128 + t * 16);
            const float* xq = x + ln * IN_F + cc + t * 32 + lk * 8;
            const float4_t a0 = *(const float4_t*)(xq);
            const float4_t a1 = *(const float4_t*)(xq + 4);
            half8 af;
            h2 p0 = cvt2(a0.x, a0.y), p1 = cvt2(a0.z, a0.w);
            h2 p2 = cvt2(a1.x, a1.y), p3 = cvt2(a1.z, a1.w);
            af[0]=p0[0]; af[1]=p0[1]; af[2]=p1[0]; af[3]=p1[1];
            af[4]=p2[0]; af[5]=p2[1]; af[6]=p3[0]; af[7]=p3[1];
            const int gi = t >> 2;
            uint4_t bw;
            #pragma unroll
            for (int i = 0; i < 4; ++i) {
                const unsigned pv = (unsigned)v[i];
                const unsigned u = (pv & 0xFu) | ((pv << 12) & 0xF0000u)
                                 | 0x64006400u;
                h2 q = __builtin_bit_cast(h2, u) - k1024;
                h2 w = q * s2[gi] + c2[gi];
                bw[i] = __builtin_bit_cast(unsigned, w);
            }
            acc = __builtin_amdgcn_mfma_f32_16x16x32_f16(
                af, __builtin_bit_cast(half8, bw), acc, 0, 0, 0);
        }
    }

    __shared__ float red[4][16][17];
    #pragma unroll
    for (int r = 0; r < 4; ++r) red[wave][lk * 4 + r][ln] = acc[r];
    __syncthreads();
    const int row = tid >> 4, col = tid & 15;
    const float sum = red[0][row][col] + red[1][row][col]
                    + red[2][row][col] + red[3][row][col];
    const int oo = otile * 16 + col;
    out[row * OUT_F + oo] = sum + bias[oo];
}

extern "C" void kernel_launch(void* const* d_in, const int* in_sizes, int n_in,
                              void* d_out, int out_size, void* d_ws, size_t ws_size,
                              hipStream_t stream) {
    const float* x      = (const float*)d_in[0];
    const int*   qwgt   = (const int*)d_in[1];
    const float* scales = (const float*)d_in[2];
    const float* zeros  = (const float*)d_in[3];
    const float* bias   = (const float*)d_in[4];
    float* out = (float*)d_out;

    const int nOTiles = OUT_F / 16;                    // 688

    if (d_ws && ws_size >= (size_t)(1 << 20)) {
        _Float16* xp = (_Float16*)d_ws;                // 128 KB f16 x table
        hipLaunchKernelGGL(xcvt_perm, dim3(32), dim3(256), 0, stream, x, xp);
        hipLaunchKernelGGL(gptq_gemm_full, dim3(nOTiles), dim3(512), 0, stream,
                           xp, qwgt, scales, zeros, bias, out);
    } else {
        hipLaunchKernelGGL(gptq_gemm_fb, dim3(nOTiles), dim3(256), 0, stream,
                           x, qwgt, scales, zeros, bias, out);
    }
}

// Round 14
// 31.013 us; speedup vs baseline: 2.2305x; 1.0800x over previous
//
#include <hip/hip_runtime.h>
#include <hip/hip_fp16.h>

#define IN_F   4096
#define OUT_F  11008
#define BATCH  16
#define GROUPS 32                    // 4096 / 128
#define PPR    2048                  // packed int32 per output row (IN_F/2)

typedef __attribute__((ext_vector_type(8))) _Float16 half8;
typedef __attribute__((ext_vector_type(2))) _Float16 h2;
typedef __attribute__((ext_vector_type(4))) float    float4_t;
typedef __attribute__((ext_vector_type(4))) int      int4_t;
typedef __attribute__((ext_vector_type(4))) unsigned uint4_t;

__device__ inline h2 cvt2(float a, float b) {
    return __builtin_bit_cast(h2, __builtin_amdgcn_cvt_pkrtz(a, b));
}

// ---- pre-pass: x (16x4096 f32) -> f16 table in FRAGMENT order ----
// step s (32 k-cols), lane l: xp[s*512 + l*8 .. +8) = f16 x[b=l&15]
// [k = s*32 + (l>>4)*8 .. +8). Gemm A-fragment load = ONE contiguous 1KB req.
__global__ __launch_bounds__(256) void xcvt_perm(const float* __restrict__ x,
                                                 _Float16* __restrict__ xp) {
    const int T = blockIdx.x * 256 + threadIdx.x;   // 8192 threads
    const int step = T >> 6, lane = T & 63;
    const int b = lane & 15, k = step * 32 + (lane >> 4) * 8;
    const float4_t a0 = *(const float4_t*)(x + b * IN_F + k);
    const float4_t a1 = *(const float4_t*)(x + b * IN_F + k + 4);
    half8 h;
    h2 p0 = cvt2(a0.x, a0.y), p1 = cvt2(a0.z, a0.w);
    h2 p2 = cvt2(a1.x, a1.y), p3 = cvt2(a1.z, a1.w);
    h[0]=p0[0]; h[1]=p0[1]; h[2]=p1[0]; h[3]=p1[1];
    h[4]=p2[0]; h[5]=p2[1]; h[6]=p3[0]; h[7]=p3[1];
    *(half8*)(xp + step * 512 + lane * 8) = h;
}

// ---- main: MAX WAVES, ZERO BARRIERS, ZERO LDS (H-TLP experiment).
// 5504 one-wave blocks = 21.5 waves/CU. Block (otile, kq): 16 o-rows x
// 512 k-cols (= 4 sub-chunks of 128 cols = 1 quant-group = 4 MFMA steps).
// 2-deep rolling register pipeline, vmcnt(8) steady state, loads never
// drained until the last sub-chunk. Partials to ws; reduce kernel sums 8.
__global__ __launch_bounds__(64, 5) void gptq_gemm_s8(
    const _Float16* __restrict__ xp, const int* __restrict__ qw,
    const float* __restrict__ scales, const float* __restrict__ zeros,
    float* __restrict__ ws_part)
{
    const int lane  = threadIdx.x;       // 0..63
    const int otile = blockIdx.x >> 3;
    const int kq    = blockIdx.x & 7;    // 512-col slice of K

    const int ln = lane & 15;            // o within tile
    const int lk = lane >> 4;            // k-subslice 0..3
    const int o  = otile * 16 + ln;

    // group constants: sub-chunk c (128 cols) <-> group kq*4 + c
    const float4_t sf = *(const float4_t*)(scales + o * GROUPS + kq * 4);
    const float4_t zf = *(const float4_t*)(zeros  + o * GROUPS + kq * 4);
    h2 s2g[4], c2g[4];
    {
        const float sa[4] = { sf.x, sf.y, sf.z, sf.w };
        const float za[4] = { zf.x, zf.y, zf.z, zf.w };
        #pragma unroll
        for (int c = 0; c < 4; ++c) {
            s2g[c] = cvt2(sa[c], sa[c]);
            c2g[c] = cvt2(-za[c] * sa[c], -za[c] * sa[c]);
        }
    }
    const h2 k1024 = { (_Float16)1024.0f, (_Float16)1024.0f };

    asm volatile("s_waitcnt vmcnt(0)" ::: "memory");   // const loads retired
    __builtin_amdgcn_sched_barrier(0);                 // -> vmcnt exact

    // per-lane bases (bytes)
    const char* qb = (const char*)(qw + o * PPR + kq * 256 + lk * 4);
    const char* xb = (const char*)xp + (kq * 16) * 1024 + lane * 16;

    int4_t qv[2][4];
    half8  xv[2][4];
    float4_t acc = {0.f, 0.f, 0.f, 0.f};

// load sub-chunk C into buffer B: 4 q-dwordx4 (lane's B-frags) + 4 x-frags
#define LOADSUB(C, B) { \
    const char* qc = qb + (C) * 256; \
    const char* xc = xb + (C) * 4096; \
    asm volatile("global_load_dwordx4 %0, %1, off"            : "=v"(qv[B][0]) : "v"(qc)); \
    asm volatile("global_load_dwordx4 %0, %1, off offset:64"  : "=v"(qv[B][1]) : "v"(qc)); \
    asm volatile("global_load_dwordx4 %0, %1, off offset:128" : "=v"(qv[B][2]) : "v"(qc)); \
    asm volatile("global_load_dwordx4 %0, %1, off offset:192" : "=v"(qv[B][3]) : "v"(qc)); \
    asm volatile("global_load_dwordx4 %0, %1, off"             : "=v"(xv[B][0]) : "v"(xc)); \
    asm volatile("global_load_dwordx4 %0, %1, off offset:1024" : "=v"(xv[B][1]) : "v"(xc)); \
    asm volatile("global_load_dwordx4 %0, %1, off offset:2048" : "=v"(xv[B][2]) : "v"(xc)); \
    asm volatile("global_load_dwordx4 %0, %1, off offset:3072" : "=v"(xv[B][3]) : "v"(xc)); \
    __builtin_amdgcn_sched_barrier(0); }

#define WAITV8 { asm volatile("s_waitcnt vmcnt(8)" ::: "memory"); \
                 __builtin_amdgcn_sched_barrier(0); }
#define WAITV0 { asm volatile("s_waitcnt vmcnt(0)" ::: "memory"); \
                 __builtin_amdgcn_sched_barrier(0); }

// 4 MFMA steps of sub-chunk C from buffer B (single group C)
#define COMPUTE(C, B) { \
    _Pragma("unroll") \
    for (int t = 0; t < 4; ++t) { \
        uint4_t bw; \
        _Pragma("unroll") \
        for (int i = 0; i < 4; ++i) { \
            const unsigned pv = (unsigned)qv[B][t][i]; \
            const unsigned u = (pv & 0xFu) | ((pv << 12) & 0xF0000u) \
                             | 0x64006400u;            /* {1024+qlo,1024+qhi} */ \
            h2 q = __builtin_bit_cast(h2, u) - k1024;  /* exact {qlo,qhi} */ \
            h2 w = q * s2g[C] + c2g[C];                /* v_pk_fma_f16 */ \
            bw[i] = __builtin_bit_cast(unsigned, w); \
        } \
        acc = __builtin_amdgcn_mfma_f32_16x16x32_f16( \
            xv[B][t], __builtin_bit_cast(half8, bw), acc, 0, 0, 0); \
    } }

    LOADSUB(0, 0)                //  8 in flight
    LOADSUB(1, 1)                // 16 in flight
    WAITV8  COMPUTE(0, 0) LOADSUB(2, 0)
    WAITV8  COMPUTE(1, 1) LOADSUB(3, 1)
    WAITV8  COMPUTE(2, 0)
    WAITV0  COMPUTE(3, 1)

#undef LOADSUB
#undef WAITV8
#undef WAITV0
#undef COMPUTE

    // C/D layout (m89-verified): lane holds D[row=(l>>4)*4+r][col=l&15]
    #pragma unroll
    for (int r = 0; r < 4; ++r)
        ws_part[(kq * BATCH + lk * 4 + r) * OUT_F + otile * 16 + ln] = acc[r];
}

__global__ __launch_bounds__(256) void gptq_reduce8(
    const float* __restrict__ ws_part, const float* __restrict__ bias,
    float* __restrict__ out)
{
    const int i4 = (blockIdx.x * 256 + threadIdx.x) * 4;   // 172 blocks exact
    if (i4 >= BATCH * OUT_F) return;
    const int N = BATCH * OUT_F;
    const int o = i4 % OUT_F;                              // OUT_F % 4 == 0
    float4_t s = *(const float4_t*)(bias + o);
    #pragma unroll
    for (int k = 0; k < 8; ++k)
        s += *(const float4_t*)(ws_part + k * N + i4);
    *(float4_t*)((float*)out + i4) = s;
}

// ---- fallback (no workspace): 4-wave single-pass kernel ----
__global__ __launch_bounds__(256) void gptq_gemm_fb(
    const float* __restrict__ x, const int* __restrict__ qw,
    const float* __restrict__ scales, const float* __restrict__ zeros,
    const float* __restrict__ bias, float* __restrict__ out)
{
    const int tid  = threadIdx.x;
    const int lane = tid & 63;
    const int wave = tid >> 6;
    const int otile = blockIdx.x;
    const int ln = lane & 15, lk = lane >> 4;
    const int o = otile * 16 + ln;
    const int kc0 = wave * 1024;

    const int* qbase = qw + o * PPR + (kc0 >> 1) + lk * 4;
    const float* srow = scales + o * GROUPS;
    const float* zrow = zeros  + o * GROUPS;

    float4_t acc = {0.f, 0.f, 0.f, 0.f};
    const h2 k1024 = { (_Float16)1024.0f, (_Float16)1024.0f };

    #pragma unroll
    for (int ch = 0; ch < 4; ++ch) {
        const int cc = kc0 + ch * 256;
        h2 s2[2], c2[2];
        #pragma unroll
        for (int gi = 0; gi < 2; ++gi) {
            const float s  = srow[(cc >> 7) + gi];
            const float c0 = -zrow[(cc >> 7) + gi] * s;
            s2[gi] = cvt2(s, s); c2[gi] = cvt2(c0, c0);
        }
        #pragma unroll
        for (int t = 0; t < 8; ++t) {
            const int4_t v = *(const int4_t*)(qbase + ch * 128 + t * 16);
            const float* xq = x + ln * IN_F + cc + t * 32 + lk * 8;
            const float4_t a0 = *(const float4_t*)(xq);
            const float4_t a1 = *(const float4_t*)(xq + 4);
            half8 af;
            h2 p0 = cvt2(a0.x, a0.y), p1 = cvt2(a0.z, a0.w);
            h2 p2 = cvt2(a1.x, a1.y), p3 = cvt2(a1.z, a1.w);
            af[0]=p0[0]; af[1]=p0[1]; af[2]=p1[0]; af[3]=p1[1];
            af[4]=p2[0]; af[5]=p2[1]; af[6]=p3[0]; af[7]=p3[1];
            const int gi = t >> 2;
            uint4_t bw;
            #pragma unroll
            for (int i = 0; i < 4; ++i) {
                const unsigned pv = (unsigned)v[i];
                const unsigned u = (pv & 0xFu) | ((pv << 12) & 0xF0000u)
                                 | 0x64006400u;
                h2 q = __builtin_bit_cast(h2, u) - k1024;
                h2 w = q * s2[gi] + c2[gi];
                bw[i] = __builtin_bit_cast(unsigned, w);
            }
            acc = __builtin_amdgcn_mfma_f32_16x16x32_f16(
                af, __builtin_bit_cast(half8, bw), acc, 0, 0, 0);
        }
    }

    __shared__ float red[4][16][17];
    #pragma unroll
    for (int r = 0; r < 4; ++r) red[wave][lk * 4 + r][ln] = acc[r];
    __syncthreads();
    const int row = tid >> 4, col = tid & 15;
    const float sum = red[0][row][col] + red[1][row][col]
                    + red[2][row][col] + red[3][row][col];
    const int oo = otile * 16 + col;
    out[row * OUT_F + oo] = sum + bias[oo];
}

extern "C" void kernel_launch(void* const* d_in, const int* in_sizes, int n_in,
                              void* d_out, int out_size, void* d_ws, size_t ws_size,
                              hipStream_t stream) {
    const float* x      = (const float*)d_in[0];
    const int*   qwgt   = (const int*)d_in[1];
    const float* scales = (const float*)d_in[2];
    const float* zeros  = (const float*)d_in[3];
    const float* bias   = (const float*)d_in[4];
    float* out = (float*)d_out;

    const int nOTiles = OUT_F / 16;                    // 688
    const size_t need = (size_t)8 << 20;               // 5.64MB partials + xp

    if (d_ws && ws_size >= need) {
        float*    ws_part = (float*)d_ws;                         // 5.64 MB
        _Float16* xp      = (_Float16*)((char*)d_ws + (6 << 20)); // 128 KB
        hipLaunchKernelGGL(xcvt_perm, dim3(32), dim3(256), 0, stream, x, xp);
        hipLaunchKernelGGL(gptq_gemm_s8, dim3(nOTiles * 8), dim3(64), 0, stream,
                           xp, qwgt, scales, zeros, ws_part);
        hipLaunchKernelGGL(gptq_reduce8, dim3(BATCH * OUT_F / 4 / 256),
                           dim3(256), 0, stream, ws_part, bias, out);
    } else {
        hipLaunchKernelGGL(gptq_gemm_fb, dim3(nOTiles), dim3(256), 0, stream,
                           x, qwgt, scales, zeros, bias, out);
    }
}